// Round 22
// baseline (185.169 us; speedup 1.0000x reference)
//
#include <hip/hip_runtime.h>
#include <hip/hip_bf16.h>

#define BATCH 32
#define T 1024
#define WVS 8
#define NTH 512
#define KS 16                     // steps per barrier window (R22: 8->16)
#define DOW 87                    // >=63+KS (ring lag 24); 7*87+63=672 ≡ 0 mod 16
#define BIGF 1e10f
#define K2f 14.426950408889634f   // 1/(gamma*ln2), gamma=0.1
#define GLN2f 0.0693147180559945f // gamma*ln2
#define KQTSE_ 0.1f

// ws layout (floats): 4 diagonal arrays [BATCH][T] + sdtw[32] + qtse[32] + edges
#define DG (BATCH * T)
#define OFF_AF 0
#define OFF_BF DG
#define OFF_AB (2 * DG)
#define OFF_BB (3 * DG)
#define SDTW_OFFF (4 * DG)
#define EDGE_OFF (4 * DG + 2 * BATCH)
#define EDGE_FLTS 544             // per interface (33 chunks x 16 = 528, padded)
#define WS2 ((size_t)(EDGE_OFF + 64 * EDGE_FLTS) * 4)
#define SENT_U 0xAAAAAAAAu

typedef float f32x4 __attribute__((ext_vector_type(4)));

__device__ __forceinline__ float fexp2(float x) {
    float r;
    asm("v_exp_f32 %0, %1" : "=v"(r) : "v"(x));
    return r;
}

__device__ __forceinline__ float softmin3(float a, float b, float c) {
    float m  = fminf(fminf(a, b), c);
    float M  = fmaxf(fmaxf(a, b), c);
    float md = __builtin_amdgcn_fmed3f(a, b, c);
    float mk = m * K2f;
    float e1 = fexp2(fmaf(-K2f, md, mk));
    float e2 = fexp2(fmaf(-K2f, M, mk));
    return fmaf(-GLN2f, __log2f(1.0f + e1 + e2), m);
}

__device__ __forceinline__ float lane_shr1(float old, float src) {
    return __int_as_float(__builtin_amdgcn_update_dpp(
        __float_as_int(old), __float_as_int(src), 0x138, 0xF, 0xF, false));
}

// ---- sentinel transport (R13/R15/R18-proven), 16-float (64B) chunks ----
__device__ __forceinline__ void issue_load16(const float* base, f32x4& a, f32x4& b,
                                             f32x4& c, f32x4& d) {
    asm volatile("global_load_dwordx4 %0, %4, off sc0 sc1\n\t"
                 "global_load_dwordx4 %1, %4, off offset:16 sc0 sc1\n\t"
                 "global_load_dwordx4 %2, %4, off offset:32 sc0 sc1\n\t"
                 "global_load_dwordx4 %3, %4, off offset:48 sc0 sc1"
                 : "=&v"(a), "=&v"(b), "=&v"(c), "=&v"(d) : "v"(base));
}
__device__ __forceinline__ void await_load16(f32x4& a, f32x4& b, f32x4& c, f32x4& d) {
    asm volatile("s_waitcnt vmcnt(0)" : "+v"(a), "+v"(b), "+v"(c), "+v"(d) :: "memory");
    __builtin_amdgcn_sched_barrier(0);
}
__device__ __forceinline__ bool sent1(const f32x4& a) {
    return (__float_as_uint(a.x) == SENT_U) | (__float_as_uint(a.y) == SENT_U) |
           (__float_as_uint(a.z) == SENT_U) | (__float_as_uint(a.w) == SENT_U);
}
__device__ __forceinline__ bool has_sent16(const f32x4& a, const f32x4& b,
                                           const f32x4& c, const f32x4& d) {
    return sent1(a) | sent1(b) | sent1(c) | sent1(d);
}
__device__ __forceinline__ void spin_load16(const float* base, f32x4& a, f32x4& b,
                                            f32x4& c, f32x4& d) {
    issue_load16(base, a, b, c, d);
    await_load16(a, b, c, d);
    while (has_sent16(a, b, c, d)) {
        __builtin_amdgcn_s_sleep(8);
        issue_load16(base, a, b, c, d);
        await_load16(a, b, c, d);
    }
}
__device__ __forceinline__ void store_edge16(float* base, const f32x4& a, const f32x4& b,
                                             const f32x4& c, const f32x4& d) {
    asm volatile("global_store_dwordx4 %0, %1, off sc0 sc1\n\t"
                 "global_store_dwordx4 %0, %2, off offset:16 sc0 sc1\n\t"
                 "global_store_dwordx4 %0, %3, off offset:32 sc0 sc1\n\t"
                 "global_store_dwordx4 %0, %4, off offset:48 sc0 sc1"
                 :: "v"(base), "v"(a), "v"(b), "v"(c), "v"(d) : "memory");
}

// Column-panel pipelined half-sweep at KS=16 (R21 structure, fewer windows).
// 128 blocks = 32 batch x 2 dir x 2 panel; 1 col/thread; R20 rank permutation.
// Panel 0's col-511 edge streams to panel 1 via 16-row sentinel chunks
// (producer myoff=672 -> chunks 16-aligned; lag 42 windows). Gating:
// wA=myoff>>4 (per-lane, boundary windows partially masked — R21 semantics),
// wB=(1022+2dir-512pg+23r)>>4 (lane-uniform, covers every record and every
// producer chunk: last chunk 31fw/32bw at sb 73/74 = producer wB). Records and
// merge identity byte-identical to R19/R20/R21-passing kernels.
__global__ __launch_bounds__(NTH) void sdtw_panel(const float* __restrict__ pred,
                                                  const float* __restrict__ targ,
                                                  float* __restrict__ ws) {
    __shared__ float p[T];
    __shared__ float ring[WVS - 1][T];

    const int blk = blockIdx.x;
    const int b = blk & (BATCH - 1);
    const int dir = (blk >> 5) & 1;
    const int pg = blk >> 6;
    const int tid = threadIdx.x;
    const int wv = tid >> 6;
    const int ln = tid & 63;
    const int rank = (wv < 4) ? (2 * wv) : (15 - 2 * wv);
    const int vtid = (rank << 6) + ln;      // panel-local col
    const int j = pg * 512 + vtid;          // logical col
    const int myoff = DOW * rank + ln;

    const float2 pv2 = ((const float2*)(pred + b * T))[tid];
    if (dir == 0) {
        ((float2*)p)[tid] = pv2;
    } else {
        p[T - 1 - 2 * tid] = pv2.x;
        p[T - 2 - 2 * tid] = pv2.y;
    }
    const float tj = targ[b * T + (dir ? (T - 1 - j) : j)];
    const float zcc = (j == 0) ? 0.0f : BIGF;

    const int q = (dir ? 1023 : 1021) - j;
    const int qp1 = q + 1;
    const int wA = myoff >> 4;
    const int wB = (1022 + 2 * dir - pg * 512 + 23 * rank) >> 4;
    const int nbl = ((1022 + 2 * dir - pg * 512 + 161) >> 4) + 1;  // windows this block
    const int nch = ((510 + 2 * dir) >> 4) + 1;                    // chunks: 32 fw / 33 bw

    float* eb = ws + EDGE_OFF + (b + BATCH * dir) * EDGE_FLTS;
    const bool consumer = (pg == 1) && (tid == 0);                 // rank0 ln0, col 512
    const bool producing = (pg == 0) && (rank == 7) && (ln == 63); // col 511

    float top = BIGF, corner = BIGF, rc = BIGF;
    float rA = BIGF, rB = BIGF;
    float rlg[KS];
#pragma unroll
    for (int i = 0; i < KS; ++i) rlg[i] = BIGF;

    __syncthreads();

    if (consumer) {
        f32x4 a, b4, c4, d4;
        spin_load16(eb + 3 * KS, a, b4, c4, d4);   // startup cushion (chunk 3)
        spin_load16(eb, a, b4, c4, d4);            // chunk 0
        rlg[0]=a.x; rlg[1]=a.y; rlg[2]=a.z; rlg[3]=a.w;
        rlg[4]=b4.x; rlg[5]=b4.y; rlg[6]=b4.z; rlg[7]=b4.w;
        rlg[8]=c4.x; rlg[9]=c4.y; rlg[10]=c4.z; rlg[11]=c4.w;
        rlg[12]=d4.x; rlg[13]=d4.y; rlg[14]=d4.z; rlg[15]=d4.w;
    }

    for (int sb = 0; sb < nbl; ++sb) {
        if (sb >= wA && sb <= wB) {
            const int ics = sb * KS - myoff;

            float rl[KS];
#pragma unroll
            for (int so = 0; so < KS; ++so) rl[so] = BIGF;
            if (ln == 0) {
                if (rank > 0) {
#pragma unroll
                    for (int so = 0; so < KS; ++so) rl[so] = ring[rank - 1][(ics + so) & (T - 1)];
                } else if (pg == 1) {
#pragma unroll
                    for (int so = 0; so < KS; ++so) rl[so] = rlg[so];
                }
            }

            float Dv[KS];
#pragma unroll
            for (int so = 0; so < KS; ++so) {
                const float d = p[(ics + so) & (T - 1)] - tj;
                Dv[so] = d * d;
            }

            f32x4 na, nb4, nc4, nd4;
            const bool want = consumer && (sb + 1) < nch;
            const float* basep = eb + (sb + 1) * KS;
            if (want) issue_load16(basep, na, nb4, nc4, nd4);

            float erow[KS];
#pragma unroll
            for (int so = 0; so < KS; ++so) {
                const int ic = ics + so;
                const float lf = lane_shr1(rl[so], rc);
                const bool r0 = (ic == 0);
                const float t0 = r0 ? BIGF : top;
                const float cc = r0 ? zcc : corner;

                const float c00 = Dv[so] + softmin3(cc, t0, lf);

                if (ic == q)   rA = c00;
                if (ic == qp1) rB = c00;

                rc = c00; top = c00; corner = lf;
                erow[so] = (ic <= qp1) ? c00 : 0.0f;   // zero-pad partial final chunk
                if (ln == 63 && rank < WVS - 1 && (unsigned)ic < (unsigned)T)
                    ring[rank][ic] = c00;
            }

            if (producing && ics >= 0) {
                f32x4 ea = {erow[0], erow[1], erow[2], erow[3]};
                f32x4 eb2 = {erow[4], erow[5], erow[6], erow[7]};
                f32x4 ec = {erow[8], erow[9], erow[10], erow[11]};
                f32x4 ed = {erow[12], erow[13], erow[14], erow[15]};
                store_edge16(eb + ics, ea, eb2, ec, ed);
            }

            if (want) {
                await_load16(na, nb4, nc4, nd4);
                while (has_sent16(na, nb4, nc4, nd4)) {
                    __builtin_amdgcn_s_sleep(2);
                    issue_load16(basep, na, nb4, nc4, nd4);
                    await_load16(na, nb4, nc4, nd4);
                }
                rlg[0]=na.x; rlg[1]=na.y; rlg[2]=na.z; rlg[3]=na.w;
                rlg[4]=nb4.x; rlg[5]=nb4.y; rlg[6]=nb4.z; rlg[7]=nb4.w;
                rlg[8]=nc4.x; rlg[9]=nc4.y; rlg[10]=nc4.z; rlg[11]=nc4.w;
                rlg[12]=nd4.x; rlg[13]=nd4.y; rlg[14]=nd4.z; rlg[15]=nd4.w;
            }
        }
        __syncthreads();
    }

    float* dgA = ws + (dir ? OFF_AB : OFF_AF) + b * T;
    float* dgB = ws + (dir ? OFF_BB : OFF_BF) + b * T;
    dgA[j] = rA;
    dgB[j] = rB;
}

// ---------------- R20-proven gated half-sweep (fallback when ws < WS2) ----------------
#define FB_KS 8
#define FB_DOW 71
__global__ __launch_bounds__(NTH) void sdtw_half_g(const float* __restrict__ pred,
                                                   const float* __restrict__ targ,
                                                   float* __restrict__ ws) {
    __shared__ float p[T];
    __shared__ float ring[WVS - 1][T];
    const int blk = blockIdx.x;
    const int b = blk & (BATCH - 1);
    const int dir = blk >> 5;
    const int tid = threadIdx.x;
    const int wv = tid >> 6;
    const int ln = tid & 63;
    const int rank = (wv < 4) ? (2 * wv) : (15 - 2 * wv);
    const int vtid = (rank << 6) + ln;
    const int myoff = FB_DOW * rank + ln;
    const float2 pv2 = ((const float2*)(pred + b * T))[tid];
    if (dir == 0) {
        ((float2*)p)[tid] = pv2;
    } else {
        p[T - 1 - 2 * tid] = pv2.x;
        p[T - 2 - 2 * tid] = pv2.y;
    }
    const int c0g = dir ? (T - 1 - 2 * vtid) : (2 * vtid);
    const int c1g = dir ? (T - 2 - 2 * vtid) : (2 * vtid + 1);
    const float tj0 = targ[b * T + c0g];
    const float tj1 = targ[b * T + c1g];
    const float zcc = (vtid == 0) ? 0.0f : BIGF;
    const int q = (dir ? 1023 : 1021) - 2 * vtid;
    const int nb = 128 + dir;
    const int wA = (FB_DOW * rank) >> 3;
    const int wB = (1022 + 2 * dir - 57 * rank) >> 3;
    float top0 = BIGF, top1 = BIGF, corner = BIGF, rc = BIGF;
    float rA0 = BIGF, rB0 = BIGF, rA1 = BIGF, rB1 = BIGF;
    __syncthreads();
    for (int sb = 0; sb < nb; ++sb) {
        if (sb >= wA && sb <= wB) {
            const int ics = sb * FB_KS - myoff;
            float rl[FB_KS];
#pragma unroll
            for (int so = 0; so < FB_KS; ++so) rl[so] = BIGF;
            if (ln == 0 && rank > 0) {
#pragma unroll
                for (int so = 0; so < FB_KS; ++so) rl[so] = ring[rank - 1][(ics + so) & (T - 1)];
            }
            float Dv0[FB_KS], Dv1[FB_KS];
#pragma unroll
            for (int so = 0; so < FB_KS; ++so) {
                const float pr = p[(ics + so) & (T - 1)];
                const float d0 = pr - tj0;
                const float d1 = pr - tj1;
                Dv0[so] = d0 * d0;
                Dv1[so] = d1 * d1;
            }
#pragma unroll
            for (int so = 0; so < FB_KS; ++so) {
                const int ic = ics + so;
                const float lf = lane_shr1(rl[so], rc);
                const bool r0 = (ic == 0);
                const float t0 = r0 ? BIGF : top0;
                const float t1 = r0 ? BIGF : top1;
                const float cc = r0 ? zcc : corner;
                const float c00 = Dv0[so] + softmin3(cc, t0, lf);
                const float c01 = Dv1[so] + softmin3(t0, t1, c00);
                if (ic == q - 1) rA1 = c01;
                if (ic == q)     { rA0 = c00; rB1 = c01; }
                if (ic == q + 1) rB0 = c00;
                rc = c01; top0 = c00; top1 = c01; corner = lf;
                if (ln == 63 && rank < WVS - 1 && (unsigned)ic < (unsigned)T)
                    ring[rank][ic] = c01;
            }
        }
        __syncthreads();
    }
    float* dgA = ws + (dir ? OFF_AB : OFF_AF) + b * T;
    float* dgB = ws + (dir ? OFF_BB : OFF_BF) + b * T;
    dgA[2 * vtid] = rA0;
    dgA[2 * vtid + 1] = rA1;
    dgB[2 * vtid] = rB0;
    dgB[2 * vtid + 1] = rB1;
}

// Merge (R19/R20/R21-passing identity) + batch QTSE partial.
__global__ __launch_bounds__(1024) void merge_kernel(const float* __restrict__ pred,
                                                     const float* __restrict__ targ,
                                                     float* __restrict__ ws) {
    const int b = blockIdx.x;
    const int tid = threadIdx.x;
    const float* dgAf = ws + OFF_AF + b * T;
    const float* dgBf = ws + OFF_BF + b * T;
    const float* dgAb = ws + OFF_AB + b * T;
    const float* dgBb = ws + OFF_BB + b * T;

    float t1 = BIGF, t2 = BIGF;
    if (tid >= 1) {
        const float d = pred[b * T + tid - 1] - targ[b * T + 1023 - tid];
        t1 = dgBf[1023 - tid] + dgBb[tid] - d * d;
    }
    if (tid >= 1 && tid <= 1022) {
        t2 = dgAf[1022 - tid] + dgAb[tid];
    }
    const float e = pred[b * T + tid] - targ[b * T + tid];
    float qacc = e * e * __expf(KQTSE_ * e);

    __shared__ float red[16];
    __shared__ float redq[16];
    __shared__ float bcast;
    const int wv = tid >> 6, ln = tid & 63;

    float mn = fminf(t1, t2);
    for (int off = 32; off; off >>= 1) mn = fminf(mn, __shfl_xor(mn, off, 64));
    if (ln == 0) red[wv] = mn;
    __syncthreads();
    if (tid == 0) {
        float m = red[0];
        for (int w = 1; w < 16; ++w) m = fminf(m, red[w]);
        bcast = m;
    }
    __syncthreads();
    const float m = bcast;

    float s = fexp2((m - t1) * K2f) + fexp2((m - t2) * K2f);
    for (int off = 32; off; off >>= 1) s += __shfl_xor(s, off, 64);
    for (int off = 32; off; off >>= 1) qacc += __shfl_xor(qacc, off, 64);
    __syncthreads();
    if (ln == 0) { red[wv] = s; redq[wv] = qacc; }
    __syncthreads();
    if (tid == 0) {
        float tot = 0.0f, qt = 0.0f;
        for (int w = 0; w < 16; ++w) { tot += red[w]; qt += redq[w]; }
        ws[SDTW_OFFF + b] = fmaf(-GLN2f, __log2f(tot), m);
        ws[SDTW_OFFF + BATCH + b] = qt;
    }
}

__global__ __launch_bounds__(64) void finish_small(const float* __restrict__ sd,
                                                   float* __restrict__ out) {
    const int l = threadIdx.x;
    float s = (l < BATCH) ? sd[l] : 0.0f;
    float qv = (l < BATCH) ? sd[BATCH + l] : 0.0f;
    for (int off = 32; off; off >>= 1) {
        s += __shfl_down(s, off, 64);
        qv += __shfl_down(qv, off, 64);
    }
    if (l == 0) out[0] = 0.1f * (s / (float)BATCH) + qv / (float)(BATCH * T);
}

extern "C" void kernel_launch(void* const* d_in, const int* in_sizes, int n_in,
                              void* d_out, int out_size, void* d_ws, size_t ws_size,
                              hipStream_t stream) {
    const float* pred = (const float*)d_in[0];
    const float* targ = (const float*)d_in[1];
    float* out = (float*)d_out;
    float* ws = (float*)d_ws;

    if (ws_size >= WS2) {
        hipMemsetAsync((char*)d_ws + EDGE_OFF * 4, 0xAA, 64 * EDGE_FLTS * 4, stream);
        sdtw_panel<<<BATCH * 4, NTH, 0, stream>>>(pred, targ, ws);
    } else {
        sdtw_half_g<<<BATCH * 2, NTH, 0, stream>>>(pred, targ, ws);
    }
    merge_kernel<<<BATCH, 1024, 0, stream>>>(pred, targ, ws);
    finish_small<<<1, 64, 0, stream>>>(ws + SDTW_OFFF, out);
}

// Round 23
// 171.597 us; speedup vs baseline: 1.0791x; 1.0791x over previous
//
#include <hip/hip_runtime.h>
#include <hip/hip_bf16.h>

#define BATCH 32
#define T 1024
#define WVS 8
#define NTH 512
#define KS 8
#define DOW 71                    // inter-rank offset (63 + KS, ring proof)
#define BIGF 1e10f
#define K2f 14.426950408889634f   // 1/(gamma*ln2), gamma=0.1
#define GLN2f 0.0693147180559945f // gamma*ln2
#define KQTSE_ 0.1f

// ws layout (floats): 4 diagonal arrays [BATCH][T] + sdtw[32] + qtse[32] + edges
#define DG (BATCH * T)
#define OFF_AF 0
#define OFF_BF DG
#define OFF_AB (2 * DG)
#define OFF_BB (3 * DG)
#define SDTW_OFFF (4 * DG)
#define EDGE_OFF (4 * DG + 2 * BATCH)
#define EDGE_FLTS 544             // per interface (65 chunks max + pad)
#define WS1 ((size_t)(4 * DG + 2 * BATCH) * 4)
#define WS2 ((size_t)(EDGE_OFF + 64 * EDGE_FLTS) * 4)
#define SENT_U 0xAAAAAAAAu

typedef float f32x4 __attribute__((ext_vector_type(4)));

__device__ __forceinline__ float fexp2(float x) {
    float r;
    asm("v_exp_f32 %0, %1" : "=v"(r) : "v"(x));
    return r;
}

__device__ __forceinline__ float softmin3(float a, float b, float c) {
    float m  = fminf(fminf(a, b), c);
    float M  = fmaxf(fmaxf(a, b), c);
    float md = __builtin_amdgcn_fmed3f(a, b, c);
    float mk = m * K2f;
    float e1 = fexp2(fmaf(-K2f, md, mk));
    float e2 = fexp2(fmaf(-K2f, M, mk));
    return fmaf(-GLN2f, __log2f(1.0f + e1 + e2), m);
}

__device__ __forceinline__ float lane_shr1(float old, float src) {
    return __int_as_float(__builtin_amdgcn_update_dpp(
        __float_as_int(old), __float_as_int(src), 0x138, 0xF, 0xF, false));
}

// ---- sentinel transport (R13/R15/R18-proven), 8-float chunks ----
__device__ __forceinline__ void issue_load8(const float* base, f32x4& a, f32x4& b) {
    asm volatile("global_load_dwordx4 %0, %2, off sc0 sc1\n\t"
                 "global_load_dwordx4 %1, %2, off offset:16 sc0 sc1"
                 : "=&v"(a), "=&v"(b) : "v"(base));
}
__device__ __forceinline__ void await_load8(f32x4& a, f32x4& b) {
    asm volatile("s_waitcnt vmcnt(0)" : "+v"(a), "+v"(b) :: "memory");
    __builtin_amdgcn_sched_barrier(0);
}
__device__ __forceinline__ bool has_sent(const f32x4& a, const f32x4& b) {
    return (__float_as_uint(a.x) == SENT_U) | (__float_as_uint(a.y) == SENT_U) |
           (__float_as_uint(a.z) == SENT_U) | (__float_as_uint(a.w) == SENT_U) |
           (__float_as_uint(b.x) == SENT_U) | (__float_as_uint(b.y) == SENT_U) |
           (__float_as_uint(b.z) == SENT_U) | (__float_as_uint(b.w) == SENT_U);
}
__device__ __forceinline__ void spin_load8(const float* base, f32x4& a, f32x4& b) {
    issue_load8(base, a, b);
    await_load8(a, b);
    while (has_sent(a, b)) {
        __builtin_amdgcn_s_sleep(8);
        issue_load8(base, a, b);
        await_load8(a, b);
    }
}
__device__ __forceinline__ void store_edge8(float* base, const f32x4& a, const f32x4& b) {
    asm volatile("global_store_dwordx4 %0, %1, off sc0 sc1\n\t"
                 "global_store_dwordx4 %0, %2, off offset:16 sc0 sc1"
                 :: "v"(base), "v"(a), "v"(b) : "memory");
}

// Column-panel pipelined half-sweep: 128 blocks = 32 batch x 2 dir x 2 panel.
// Panel pg owns logical cols [pg*512, pg*512+512), 1 col/thread, 8 waves with
// the R20 rank permutation + window gating. Panel 0's col-511 edge streams to
// panel 1's rank-0 lane-0 via sentinel chunks. Records (rA at ic==q, rB at
// ic==q+1, q=(dir?1023:1021)-j) and exports dgA[j]=cell(q,j), dgB[j]=cell(q+1,j)
// match the R19-verified merge identity. (R21-passing kernel, verbatim.)
__global__ __launch_bounds__(NTH) void sdtw_panel(const float* __restrict__ pred,
                                                  const float* __restrict__ targ,
                                                  float* __restrict__ ws) {
    __shared__ float p[T];
    __shared__ float ring[WVS - 1][T];

    const int blk = blockIdx.x;
    const int b = blk & (BATCH - 1);
    const int dir = (blk >> 5) & 1;
    const int pg = blk >> 6;
    const int tid = threadIdx.x;
    const int wv = tid >> 6;
    const int ln = tid & 63;
    const int rank = (wv < 4) ? (2 * wv) : (15 - 2 * wv);
    const int vtid = (rank << 6) + ln;      // panel-local col
    const int j = pg * 512 + vtid;          // logical col
    const int myoff = DOW * rank + ln;

    const float2 pv2 = ((const float2*)(pred + b * T))[tid];
    if (dir == 0) {
        ((float2*)p)[tid] = pv2;
    } else {
        p[T - 1 - 2 * tid] = pv2.x;
        p[T - 2 - 2 * tid] = pv2.y;
    }
    const float tj = targ[b * T + (dir ? (T - 1 - j) : j)];
    const float zcc = (j == 0) ? 0.0f : BIGF;

    const int q = (dir ? 1023 : 1021) - j;
    const int qp1 = q + 1;
    const int wA = myoff >> 3;
    const int wB = (1022 + 2 * dir - pg * 512 + 7 * rank) >> 3;
    const int nbl = ((1022 + 2 * dir - pg * 512 + 49) >> 3) + 1;   // windows this block
    const int nch = ((510 + 2 * dir) >> 3) + 1;                    // chunks per interface

    float* eb = ws + EDGE_OFF + (b + BATCH * dir) * EDGE_FLTS;
    const bool consumer = (pg == 1) && (tid == 0);                 // rank0 ln0, col 512
    const bool producing = (pg == 0) && (rank == 7) && (ln == 63); // col 511

    float top = BIGF, corner = BIGF, rc = BIGF;
    float rA = BIGF, rB = BIGF;
    float rlg[KS];
#pragma unroll
    for (int i = 0; i < KS; ++i) rlg[i] = BIGF;

    __syncthreads();

    if (consumer) {
        f32x4 a, b4;
        spin_load8(eb + 3 * KS, a, b4);   // startup cushion (chunk 3)
        spin_load8(eb, a, b4);            // chunk 0
        rlg[0] = a.x; rlg[1] = a.y; rlg[2] = a.z; rlg[3] = a.w;
        rlg[4] = b4.x; rlg[5] = b4.y; rlg[6] = b4.z; rlg[7] = b4.w;
    }

    for (int sb = 0; sb < nbl; ++sb) {
        if (sb >= wA && sb <= wB) {
            const int ics = sb * KS - myoff;

            float rl[KS];
#pragma unroll
            for (int so = 0; so < KS; ++so) rl[so] = BIGF;
            if (ln == 0) {
                if (rank > 0) {
#pragma unroll
                    for (int so = 0; so < KS; ++so) rl[so] = ring[rank - 1][(ics + so) & (T - 1)];
                } else if (pg == 1) {
#pragma unroll
                    for (int so = 0; so < KS; ++so) rl[so] = rlg[so];
                }
            }

            float Dv[KS];
#pragma unroll
            for (int so = 0; so < KS; ++so) {
                const float d = p[(ics + so) & (T - 1)] - tj;
                Dv[so] = d * d;
            }

            f32x4 na, nb4;
            const bool want = consumer && (sb + 1) < nch;
            const float* basep = eb + (sb + 1) * KS;
            if (want) issue_load8(basep, na, nb4);

            float erow[KS];
#pragma unroll
            for (int so = 0; so < KS; ++so) {
                const int ic = ics + so;
                const float lf = lane_shr1(rl[so], rc);
                const bool r0 = (ic == 0);
                const float t0 = r0 ? BIGF : top;
                const float cc = r0 ? zcc : corner;

                const float c00 = Dv[so] + softmin3(cc, t0, lf);

                if (ic == q)   rA = c00;
                if (ic == qp1) rB = c00;

                rc = c00; top = c00; corner = lf;
                erow[so] = (ic <= qp1) ? c00 : 0.0f;   // zero-pad partial final chunk
                if (ln == 63 && rank < WVS - 1 && (unsigned)ic < (unsigned)T)
                    ring[rank][ic] = c00;
            }

            if (producing && ics >= 0) {
                f32x4 ea = {erow[0], erow[1], erow[2], erow[3]};
                f32x4 eb2 = {erow[4], erow[5], erow[6], erow[7]};
                store_edge8(eb + ics, ea, eb2);
            }

            if (want) {
                await_load8(na, nb4);
                while (has_sent(na, nb4)) {
                    __builtin_amdgcn_s_sleep(2);
                    issue_load8(basep, na, nb4);
                    await_load8(na, nb4);
                }
                rlg[0] = na.x; rlg[1] = na.y; rlg[2] = na.z; rlg[3] = na.w;
                rlg[4] = nb4.x; rlg[5] = nb4.y; rlg[6] = nb4.z; rlg[7] = nb4.w;
            }
        }
        __syncthreads();
    }

    float* dgA = ws + (dir ? OFF_AB : OFF_AF) + b * T;
    float* dgB = ws + (dir ? OFF_BB : OFF_BF) + b * T;
    dgA[j] = rA;
    dgB[j] = rB;
}

// ---------------- R20-proven gated half-sweep (fallback when ws < WS2) ----------------
__global__ __launch_bounds__(NTH) void sdtw_half_g(const float* __restrict__ pred,
                                                   const float* __restrict__ targ,
                                                   float* __restrict__ ws) {
    __shared__ float p[T];
    __shared__ float ring[WVS - 1][T];
    const int blk = blockIdx.x;
    const int b = blk & (BATCH - 1);
    const int dir = blk >> 5;
    const int tid = threadIdx.x;
    const int wv = tid >> 6;
    const int ln = tid & 63;
    const int rank = (wv < 4) ? (2 * wv) : (15 - 2 * wv);
    const int vtid = (rank << 6) + ln;
    const int myoff = DOW * rank + ln;
    const float2 pv2 = ((const float2*)(pred + b * T))[tid];
    if (dir == 0) {
        ((float2*)p)[tid] = pv2;
    } else {
        p[T - 1 - 2 * tid] = pv2.x;
        p[T - 2 - 2 * tid] = pv2.y;
    }
    const int c0g = dir ? (T - 1 - 2 * vtid) : (2 * vtid);
    const int c1g = dir ? (T - 2 - 2 * vtid) : (2 * vtid + 1);
    const float tj0 = targ[b * T + c0g];
    const float tj1 = targ[b * T + c1g];
    const float zcc = (vtid == 0) ? 0.0f : BIGF;
    const int q = (dir ? 1023 : 1021) - 2 * vtid;
    const int nb = 128 + dir;
    const int wA = (DOW * rank) >> 3;
    const int wB = (1022 + 2 * dir - 57 * rank) >> 3;
    float top0 = BIGF, top1 = BIGF, corner = BIGF, rc = BIGF;
    float rA0 = BIGF, rB0 = BIGF, rA1 = BIGF, rB1 = BIGF;
    __syncthreads();
    for (int sb = 0; sb < nb; ++sb) {
        if (sb >= wA && sb <= wB) {
            const int ics = sb * KS - myoff;
            float rl[KS];
#pragma unroll
            for (int so = 0; so < KS; ++so) rl[so] = BIGF;
            if (ln == 0 && rank > 0) {
#pragma unroll
                for (int so = 0; so < KS; ++so) rl[so] = ring[rank - 1][(ics + so) & (T - 1)];
            }
            float Dv0[KS], Dv1[KS];
#pragma unroll
            for (int so = 0; so < KS; ++so) {
                const float pr = p[(ics + so) & (T - 1)];
                const float d0 = pr - tj0;
                const float d1 = pr - tj1;
                Dv0[so] = d0 * d0;
                Dv1[so] = d1 * d1;
            }
#pragma unroll
            for (int so = 0; so < KS; ++so) {
                const int ic = ics + so;
                const float lf = lane_shr1(rl[so], rc);
                const bool r0 = (ic == 0);
                const float t0 = r0 ? BIGF : top0;
                const float t1 = r0 ? BIGF : top1;
                const float cc = r0 ? zcc : corner;
                const float c00 = Dv0[so] + softmin3(cc, t0, lf);
                const float c01 = Dv1[so] + softmin3(t0, t1, c00);
                if (ic == q - 1) rA1 = c01;
                if (ic == q)     { rA0 = c00; rB1 = c01; }
                if (ic == q + 1) rB0 = c00;
                rc = c01; top0 = c00; top1 = c01; corner = lf;
                if (ln == 63 && rank < WVS - 1 && (unsigned)ic < (unsigned)T)
                    ring[rank][ic] = c01;
            }
        }
        __syncthreads();
    }
    float* dgA = ws + (dir ? OFF_AB : OFF_AF) + b * T;
    float* dgB = ws + (dir ? OFF_BB : OFF_BF) + b * T;
    dgA[2 * vtid] = rA0;
    dgA[2 * vtid + 1] = rA1;
    dgB[2 * vtid] = rB0;
    dgB[2 * vtid + 1] = rB1;
}

// Merge (R19/R20/R21-passing identity) + batch QTSE partial.
__global__ __launch_bounds__(1024) void merge_kernel(const float* __restrict__ pred,
                                                     const float* __restrict__ targ,
                                                     float* __restrict__ ws) {
    const int b = blockIdx.x;
    const int tid = threadIdx.x;
    const float* dgAf = ws + OFF_AF + b * T;
    const float* dgBf = ws + OFF_BF + b * T;
    const float* dgAb = ws + OFF_AB + b * T;
    const float* dgBb = ws + OFF_BB + b * T;

    float t1 = BIGF, t2 = BIGF;
    if (tid >= 1) {
        const float d = pred[b * T + tid - 1] - targ[b * T + 1023 - tid];
        t1 = dgBf[1023 - tid] + dgBb[tid] - d * d;
    }
    if (tid >= 1 && tid <= 1022) {
        t2 = dgAf[1022 - tid] + dgAb[tid];
    }
    const float e = pred[b * T + tid] - targ[b * T + tid];
    float qacc = e * e * __expf(KQTSE_ * e);

    __shared__ float red[16];
    __shared__ float redq[16];
    __shared__ float bcast;
    const int wv = tid >> 6, ln = tid & 63;

    float mn = fminf(t1, t2);
    for (int off = 32; off; off >>= 1) mn = fminf(mn, __shfl_xor(mn, off, 64));
    if (ln == 0) red[wv] = mn;
    __syncthreads();
    if (tid == 0) {
        float m = red[0];
        for (int w = 1; w < 16; ++w) m = fminf(m, red[w]);
        bcast = m;
    }
    __syncthreads();
    const float m = bcast;

    float s = fexp2((m - t1) * K2f) + fexp2((m - t2) * K2f);
    for (int off = 32; off; off >>= 1) s += __shfl_xor(s, off, 64);
    for (int off = 32; off; off >>= 1) qacc += __shfl_xor(qacc, off, 64);
    __syncthreads();
    if (ln == 0) { red[wv] = s; redq[wv] = qacc; }
    __syncthreads();
    if (tid == 0) {
        float tot = 0.0f, qt = 0.0f;
        for (int w = 0; w < 16; ++w) { tot += red[w]; qt += redq[w]; }
        ws[SDTW_OFFF + b] = fmaf(-GLN2f, __log2f(tot), m);
        ws[SDTW_OFFF + BATCH + b] = qt;
    }
}

__global__ __launch_bounds__(64) void finish_small(const float* __restrict__ sd,
                                                   float* __restrict__ out) {
    const int l = threadIdx.x;
    float s = (l < BATCH) ? sd[l] : 0.0f;
    float qv = (l < BATCH) ? sd[BATCH + l] : 0.0f;
    for (int off = 32; off; off >>= 1) {
        s += __shfl_down(s, off, 64);
        qv += __shfl_down(qv, off, 64);
    }
    if (l == 0) out[0] = 0.1f * (s / (float)BATCH) + qv / (float)(BATCH * T);
}

extern "C" void kernel_launch(void* const* d_in, const int* in_sizes, int n_in,
                              void* d_out, int out_size, void* d_ws, size_t ws_size,
                              hipStream_t stream) {
    const float* pred = (const float*)d_in[0];
    const float* targ = (const float*)d_in[1];
    float* out = (float*)d_out;
    float* ws = (float*)d_ws;

    if (ws_size >= WS2) {
        hipMemsetAsync((char*)d_ws + EDGE_OFF * 4, 0xAA, 64 * EDGE_FLTS * 4, stream);
        sdtw_panel<<<BATCH * 4, NTH, 0, stream>>>(pred, targ, ws);
    } else {
        sdtw_half_g<<<BATCH * 2, NTH, 0, stream>>>(pred, targ, ws);
    }
    merge_kernel<<<BATCH, 1024, 0, stream>>>(pred, targ, ws);
    finish_small<<<1, 64, 0, stream>>>(ws + SDTW_OFFF, out);
}